// Round 5
// baseline (1034.994 us; speedup 1.0000x reference)
//
#include <hip/hip_runtime.h>
#include <math.h>

#define D_MODEL 512
#define NHEAD   8
#define DKH     64
#define NLAYER  6
#define FFDIM   2048
#define VOCAB   512
#define BB      4
#define SS      1024
#define NROWS   4096

typedef unsigned short ushort_t;
typedef short short8 __attribute__((ext_vector_type(8)));
typedef float f32x4  __attribute__((ext_vector_type(4)));

__device__ __forceinline__ float bf2f(ushort_t u) {
    union { float f; unsigned int i; } x; x.i = ((unsigned int)u) << 16; return x.f;
}
__device__ __forceinline__ ushort_t f2bf(float f) {
    union { float f; unsigned int i; } x; x.f = f;
    unsigned int r = x.i + 0x7FFFu + ((x.i >> 16) & 1u);
    return (ushort_t)(r >> 16);
}
__device__ __forceinline__ void gload_lds16(const void* g, void* l) {
    __builtin_amdgcn_global_load_lds(
        (const __attribute__((address_space(1))) void*)g,
        (__attribute__((address_space(3))) void*)l, 16, 0, 0);
}

// ------------------------------------------------------------- weight convert
__global__ __launch_bounds__(256) void cvt_layer(
    const float* __restrict__ wq, const float* __restrict__ wk, const float* __restrict__ wv,
    const float* __restrict__ wo, const float* __restrict__ w1, const float* __restrict__ w2,
    const float* __restrict__ bq, const float* __restrict__ bk, const float* __restrict__ bv,
    ushort_t* __restrict__ wl, float* __restrict__ bqkv)
{
    int idx = blockIdx.x * 256 + threadIdx.x;   // quad id, 786432 total
    int e = idx * 4;
    float4 v;
    if (e < 786432) {
        if (e < 262144)       v = *(const float4*)(wq + e);
        else if (e < 524288)  v = *(const float4*)(wk + (e - 262144));
        else                  v = *(const float4*)(wv + (e - 524288));
    } else if (e < 1048576)   v = *(const float4*)(wo + (e - 786432));
    else if (e < 2097152)     v = *(const float4*)(w1 + (e - 1048576));
    else                      v = *(const float4*)(w2 + (e - 2097152));
    union { ushort_t u[4]; uint2 q; } pk;
    pk.u[0] = f2bf(v.x); pk.u[1] = f2bf(v.y); pk.u[2] = f2bf(v.z); pk.u[3] = f2bf(v.w);
    *(uint2*)(wl + e) = pk.q;
    if (idx < 384) {
        int b4 = idx * 4;
        float4 bv4;
        if (b4 < 512)       bv4 = *(const float4*)(bq + b4);
        else if (b4 < 1024) bv4 = *(const float4*)(bk + (b4 - 512));
        else                bv4 = *(const float4*)(bv + (b4 - 1024));
        *(float4*)(bqkv + b4) = bv4;
    }
}

__global__ __launch_bounds__(256) void cvt_simple(
    const float* __restrict__ src, ushort_t* __restrict__ dst)
{
    int e = (blockIdx.x * 256 + threadIdx.x) * 4;
    float4 v = *(const float4*)(src + e);
    union { ushort_t u[4]; uint2 q; } pk;
    pk.u[0] = f2bf(v.x); pk.u[1] = f2bf(v.y); pk.u[2] = f2bf(v.z); pk.u[3] = f2bf(v.w);
    *(uint2*)(dst + e) = pk.q;
}

// mask bias: am ? 0 : -1e9  (tiny, L1-resident during attention)
__global__ __launch_bounds__(256) void maskbias_kernel(
    const int* __restrict__ am, float* __restrict__ mb)
{
    int i = blockIdx.x * 256 + threadIdx.x;
    if (i < NROWS) mb[i] = am[i] ? 0.f : -1e9f;
}

// ---------------------------------------------------------------- embedding
__global__ __launch_bounds__(512) void embed_kernel(
    const int* __restrict__ ids, const float* __restrict__ emb,
    float* __restrict__ xf, ushort_t* __restrict__ xb)
{
    int row = blockIdx.x;
    int d   = threadIdx.x;
    int s   = row & (SS - 1);
    int tok = ids[row];
    float div = expf(-(float)(d & ~1) * 0.0179889460390586f);
    float arg = (float)s * div;
    float pe  = (d & 1) ? cosf(arg) : sinf(arg);
    float v = emb[(size_t)tok * D_MODEL + d] * 22.62741699796952f + pe;
    xf[(size_t)row * D_MODEL + d] = v;
    xb[(size_t)row * D_MODEL + d] = f2bf(v);
}

// ---------------------------------------------------------------- layernorm
__global__ __launch_bounds__(512) void ln_kernel(
    const float* __restrict__ x, const float* __restrict__ g,
    const float* __restrict__ b, float* __restrict__ outf, ushort_t* __restrict__ outb)
{
    int row = blockIdx.x;
    int d   = threadIdx.x;
    int wave = d >> 6, lane = d & 63;
    __shared__ float red[8];

    float v = x[(size_t)row * D_MODEL + d];
    float s = v;
#pragma unroll
    for (int o = 32; o > 0; o >>= 1) s += __shfl_xor(s, o);
    if (lane == 0) red[wave] = s;
    __syncthreads();
    float tot = 0.f;
#pragma unroll
    for (int i = 0; i < 8; ++i) tot += red[i];
    float mu = tot * (1.0f / D_MODEL);
    float c  = v - mu;
    __syncthreads();
    float s2 = c * c;
#pragma unroll
    for (int o = 32; o > 0; o >>= 1) s2 += __shfl_xor(s2, o);
    if (lane == 0) red[wave] = s2;
    __syncthreads();
    float tot2 = 0.f;
#pragma unroll
    for (int i = 0; i < 8; ++i) tot2 += red[i];
    float var = tot2 * (1.0f / D_MODEL);
    float y = c * (1.0f / sqrtf(var + 1e-5f)) * g[d] + b[d];
    outf[(size_t)row * D_MODEL + d] = y;
    outb[(size_t)row * D_MODEL + d] = f2bf(y);
}

// ---------------------------------------------------------------- MFMA GEMM
// BK=64, 2 MFMA k-steps per staged tile (half the barrier drains of BK=32).
// LDS layout [row][64] with k8-slot XOR-swizzle: element (row, k8) lives at
// slot (k8 ^ (row&7)). global_load_lds dest stays linear; the SOURCE k-offset
// is pre-swizzled (involution), ds_reads apply the same XOR -> conflict-free.
template<int BM, int BN, bool RELU, bool RES, bool OBF16, bool VT>
__global__ __launch_bounds__(256) void gemm_kernel(
    const ushort_t* __restrict__ A, const ushort_t* __restrict__ W,
    const float* __restrict__ bias, const float* __restrict__ res,
    void* __restrict__ out, ushort_t* __restrict__ vtg, int M, int N, int K)
{
    constexpr int WMT = BM / 2, WNT = BN / 2;
    constexpr int FM = WMT / 16, FN = WNT / 16;
    constexpr int ISSA = BM / 32, ISSB = BN / 32;
    __shared__ ushort_t As[BM * 64];
    __shared__ ushort_t Bs[BN * 64];

    const int t = threadIdx.x;
    const int w = t >> 6, lane = t & 63;
    const int wr = w >> 1, wc = w & 1;
    const int col0 = blockIdx.x * BN;
    const int row0 = blockIdx.y * BM;
    const int lrow = lane & 15, kg = lane >> 4;
    const int srow = t >> 3;                       // 0..31
    const int sk8  = (t & 7) ^ ((t >> 3) & 7);     // pre-swizzled source k8

    f32x4 acc[FM][FN];
#pragma unroll
    for (int m = 0; m < FM; ++m)
#pragma unroll
        for (int n = 0; n < FN; ++n) acc[m][n] = (f32x4){0.f, 0.f, 0.f, 0.f};

    for (int k0 = 0; k0 < K; k0 += 64) {
#pragma unroll
        for (int i = 0; i < ISSA; ++i)
            gload_lds16(A + (size_t)(row0 + i * 32 + srow) * K + k0 + sk8 * 8,
                        (char*)As + i * 4096 + t * 16);
#pragma unroll
        for (int i = 0; i < ISSB; ++i)
            gload_lds16(W + (size_t)(col0 + i * 32 + srow) * K + k0 + sk8 * 8,
                        (char*)Bs + i * 4096 + t * 16);
        __syncthreads();
#pragma unroll
        for (int kk = 0; kk < 2; ++kk) {
            short8 af[FM], bfv[FN];
#pragma unroll
            for (int m = 0; m < FM; ++m) {
                const int row = wr * WMT + m * 16 + lrow;
                af[m] = *(const short8*)&As[row * 64 + (((kk * 4 + kg) ^ (lrow & 7)) << 3)];
            }
#pragma unroll
            for (int n = 0; n < FN; ++n) {
                const int col = wc * WNT + n * 16 + lrow;
                bfv[n] = *(const short8*)&Bs[col * 64 + (((kk * 4 + kg) ^ (lrow & 7)) << 3)];
            }
#pragma unroll
            for (int m = 0; m < FM; ++m)
#pragma unroll
                for (int n = 0; n < FN; ++n)
                    acc[m][n] = __builtin_amdgcn_mfma_f32_16x16x32_bf16(
                        af[m], bfv[n], acc[m][n], 0, 0, 0);
        }
        __syncthreads();
    }

    const int lrow4 = (lane >> 4) * 4;
    const int lcol  = lane & 15;
#pragma unroll
    for (int m = 0; m < FM; ++m)
#pragma unroll
        for (int n = 0; n < FN; ++n) {
            const int col = col0 + wc * WNT + n * 16 + lcol;
            const float bv = bias ? bias[col] : 0.f;
            const int row_base = row0 + wr * WMT + m * 16 + lrow4;
            if (VT && col >= 1024) {
                // V columns: write transposed into vtg[bh][d][token]
                const int vh = (col - 1024) >> 6;
                const int vd = (col - 1024) & 63;
                const int bq = row_base >> 10;          // batch (tile never straddles)
                const int s0 = row_base & 1023;
                union { ushort_t u[4]; uint2 q; } pk;
#pragma unroll
                for (int j = 0; j < 4; ++j) pk.u[j] = f2bf(acc[m][n][j] + bv);
                *(uint2*)(vtg + ((size_t)(bq * 8 + vh) * 64 + vd) * 1024 + s0) = pk.q;
            } else {
#pragma unroll
                for (int j = 0; j < 4; ++j) {
                    const int row = row_base + j;
                    float v = acc[m][n][j] + bv;
                    if (RES)  v += res[(size_t)row * N + col];
                    if (RELU) v = fmaxf(v, 0.f);
                    if (OBF16) ((ushort_t*)out)[(size_t)row * N + col] = f2bf(v);
                    else       ((float*)out)[(size_t)row * N + col] = v;
                }
            }
        }
}

// ---------------------------------------------------------------- attention
// MFMA flash attention, ONE WAVE PER BLOCK (64 thr). 2048 blocks = 32 bh x 64
// query-subtiles of 16, issued heavy-first for balance (~8 blocks/CU sustained).
// K register-double-buffered; V just-in-time; mask as f32 bias; wave-private
// swizzled P in LDS (no barriers anywhere).
__global__ __launch_bounds__(64, 4) void attn_kernel(
    const ushort_t* __restrict__ qkv, const ushort_t* __restrict__ vtg,
    const float* __restrict__ mbias, ushort_t* __restrict__ o)
{
    __shared__ ushort_t Ps[16 * 64];

    const int l = threadIdx.x;
    const int bid = blockIdx.x;
    const int qs = 63 - (bid >> 5);        // heavy subtiles first
    const int bh = bid & 31, b = bh >> 3, h = bh & 7;
    const int q0 = qs * 16;
    const int lg = l >> 4, lr = l & 15;
    const int nt = qs >> 2;                // last k-tile index

    const ushort_t* qrow = qkv + (size_t)(b * SS + q0 + lr) * 1536 + h * 64;
    const short8 qa0 = *(const short8*)(qrow + lg * 8);
    const short8 qa1 = *(const short8*)(qrow + 32 + lg * 8);

    float m_run[4], l_run[4];
    f32x4 oacc[4];
#pragma unroll
    for (int j = 0; j < 4; ++j) { m_run[j] = -1e30f; l_run[j] = 0.f; }
#pragma unroll
    for (int nf = 0; nf < 4; ++nf) oacc[nf] = (f32x4){0.f, 0.f, 0.f, 0.f};

    ushort_t* myP = &Ps[0];
    const ushort_t* kb0 = qkv + (size_t)(b * SS) * 1536 + 512 + h * 64 + (size_t)lr * 1536 + lg * 8;
    const ushort_t* vb0 = vtg + ((size_t)bh * 64 + lr) * 1024 + lg * 8;
    const float*    mb0 = mbias + b * SS + lr;

    short8 kA[8], kB[8];
    float  mbA[4], mbB[4];

    auto PREFK = [&](short8* kf, float* mbf, int kt) {
#pragma unroll
        for (int nf = 0; nf < 4; ++nf) {
            const ushort_t* kr = kb0 + (size_t)(kt * 64 + 16 * nf) * 1536;
            kf[2 * nf]     = *(const short8*)(kr);
            kf[2 * nf + 1] = *(const short8*)(kr + 32);
            mbf[nf] = mb0[kt * 64 + 16 * nf];
        }
    };

    auto COMPUTE = [&](const short8* kf, const float* mbf, int kt) {
        short8 vf[8];
#pragma unroll
        for (int nf = 0; nf < 4; ++nf) {
            const ushort_t* vr = vb0 + (size_t)(16 * nf) * 1024 + kt * 64;
            vf[2 * nf]     = *(const short8*)(vr);
            vf[2 * nf + 1] = *(const short8*)(vr + 32);
        }
        f32x4 s[4];
#pragma unroll
        for (int nf = 0; nf < 4; ++nf) {
            f32x4 a = (f32x4){0.f, 0.f, 0.f, 0.f};
            a = __builtin_amdgcn_mfma_f32_16x16x32_bf16(qa0, kf[2 * nf],     a, 0, 0, 0);
            a = __builtin_amdgcn_mfma_f32_16x16x32_bf16(qa1, kf[2 * nf + 1], a, 0, 0, 0);
            s[nf] = a;
        }
        const int kk0 = kt * 64 + lr;
        const bool diag = (kt == nt);
        float p[4][4];
#pragma unroll
        for (int j = 0; j < 4; ++j) {
            const int qi = q0 + lg * 4 + j;
            float mx = -1e30f;
#pragma unroll
            for (int nf = 0; nf < 4; ++nf) {
                float sv = s[nf][j] * 0.125f + mbf[nf];
                if (diag && (kk0 + 16 * nf) > qi) sv = -1e9f;
                s[nf][j] = sv;
                mx = fmaxf(mx, sv);
            }
#pragma unroll
            for (int off = 1; off < 16; off <<= 1) mx = fmaxf(mx, __shfl_xor(mx, off));
            const float mnew = fmaxf(m_run[j], mx);
            float sum = 0.f;
#pragma unroll
            for (int nf = 0; nf < 4; ++nf) {
                float pv = __expf(s[nf][j] - mnew);
                p[nf][j] = pv;
                sum += pv;
            }
#pragma unroll
            for (int off = 1; off < 16; off <<= 1) sum += __shfl_xor(sum, off);
            const float rs = __expf(m_run[j] - mnew);
            l_run[j] = l_run[j] * rs + sum;
            m_run[j] = mnew;
#pragma unroll
            for (int nf = 0; nf < 4; ++nf) oacc[nf][j] *= rs;
        }
#pragma unroll
        for (int nf = 0; nf < 4; ++nf)
#pragma unroll
            for (int j = 0; j < 4; ++j) {
                const int q = lg * 4 + j;
                const int col = nf * 16 + lr;
                myP[q * 64 + (((col >> 3) ^ (q & 7)) << 3) + (col & 7)] = f2bf(p[nf][j]);
            }
        asm volatile("s_waitcnt lgkmcnt(0)" ::: "memory");
        __builtin_amdgcn_sched_barrier(0);
        const short8 pa0 = *(const short8*)&myP[lr * 64 + ((lg ^ (lr & 7)) << 3)];
        const short8 pa1 = *(const short8*)&myP[lr * 64 + (((4 + lg) ^ (lr & 7)) << 3)];
#pragma unroll
        for (int nf = 0; nf < 4; ++nf) {
            oacc[nf] = __builtin_amdgcn_mfma_f32_16x16x32_bf16(pa0, vf[2 * nf],     oacc[nf], 0, 0, 0);
            oacc[nf] = __builtin_amdgcn_mfma_f32_16x16x32_bf16(pa1, vf[2 * nf + 1], oacc[nf], 0, 0, 0);
        }
    };

    PREFK(kA, mbA, 0);
    for (int kt = 0; kt <= nt; kt += 2) {
        PREFK(kB, mbB, (kt + 1 <= nt) ? kt + 1 : nt);
        COMPUTE(kA, mbA, kt);
        if (kt + 1 <= nt) {
            PREFK(kA, mbA, (kt + 2 <= nt) ? kt + 2 : nt);
            COMPUTE(kB, mbB, kt + 1);
        }
    }

#pragma unroll
    for (int nf = 0; nf < 4; ++nf)
#pragma unroll
        for (int j = 0; j < 4; ++j) {
            const int qi = q0 + lg * 4 + j;
            const int d  = nf * 16 + lr;
            o[(size_t)(b * SS + qi) * 512 + h * 64 + d] = f2bf(oacc[nf][j] / l_run[j]);
        }
}

// ---------------------------------------------------------------- launch
extern "C" void kernel_launch(void* const* d_in, const int* in_sizes, int n_in,
                              void* d_out, int out_size, void* d_ws, size_t ws_size,
                              hipStream_t stream)
{
    const int*   ids   = (const int*)d_in[0];
    const int*   am    = (const int*)d_in[1];
    const float* emb   = (const float*)d_in[2];
    const float* wq    = (const float*)d_in[3];
    const float* bq    = (const float*)d_in[4];
    const float* wk    = (const float*)d_in[5];
    const float* bk    = (const float*)d_in[6];
    const float* wv    = (const float*)d_in[7];
    const float* bv    = (const float*)d_in[8];
    const float* wo    = (const float*)d_in[9];
    const float* bo    = (const float*)d_in[10];
    const float* ln1g  = (const float*)d_in[11];
    const float* ln1b  = (const float*)d_in[12];
    const float* w1    = (const float*)d_in[13];
    const float* b1    = (const float*)d_in[14];
    const float* w2    = (const float*)d_in[15];
    const float* b2    = (const float*)d_in[16];
    const float* ln2g  = (const float*)d_in[17];
    const float* ln2b  = (const float*)d_in[18];
    const float* lnfg  = (const float*)d_in[19];
    const float* lnfb  = (const float*)d_in[20];
    const float* lmw   = (const float*)d_in[21];

    char* base = (char*)d_ws;
    float*    h    = (float*)(base);                    //  8,388,608
    float*    h2   = (float*)(base + 8388608);          //  8,388,608 (aliased by vtg during attn)
    ushort_t* hb   = (ushort_t*)(base + 16777216);      //  4,194,304
    ushort_t* act  = (ushort_t*)(base + 20971520);      // 16,777,216 shared
    ushort_t* qkvb = act;                               //   12 MB (Q|K only used)
    ushort_t* ob   = act + 6291456;                     //    4 MB
    ushort_t* fbuf = act;                               //   16 MB (after attn phase)
    ushort_t* wl   = (ushort_t*)(base + 37748736);      //  6,291,456
    float*    bqkv = (float*)(base + 44040192);         //      6,144
    ushort_t* lmwb = (ushort_t*)(base + 44046336);      //    524,288
    float*    mbias= (float*)(base + 44570624);         //     16,384
    ushort_t* vtg  = (ushort_t*)h2;                     //    4 MB, live only during attn

    cvt_simple<<<256, 256, 0, stream>>>(lmw, lmwb);
    maskbias_kernel<<<16, 256, 0, stream>>>(am, mbias);
    embed_kernel<<<NROWS, 512, 0, stream>>>(ids, emb, h, hb);

    for (int l = 0; l < NLAYER; ++l) {
        const size_t dd = (size_t)l * 262144;
        const size_t fd = (size_t)l * 1048576;
        cvt_layer<<<3072, 256, 0, stream>>>(wq + dd, wk + dd, wv + dd, wo + dd,
                                            w1 + fd, w2 + fd,
                                            bq + l * 512, bk + l * 512, bv + l * 512,
                                            wl, bqkv);
        // QKV fused GEMM; V written transposed into vtg by the epilogue
        gemm_kernel<128, 128, false, false, true, true><<<dim3(12, 32), 256, 0, stream>>>(
            hb, wl, bqkv, nullptr, qkvb, vtg, NROWS, 1536, 512);

        attn_kernel<<<2048, 64, 0, stream>>>(qkvb, vtg, mbias, ob);

        gemm_kernel<64, 128, false, true, false, false><<<dim3(4, 64), 256, 0, stream>>>(
            ob, wl + 786432, bo + l * 512, h, h2, nullptr, NROWS, 512, 512);
        ln_kernel<<<NROWS, 512, 0, stream>>>(h2, ln1g + l * 512, ln1b + l * 512, h, hb);

        gemm_kernel<128, 128, true, false, true, false><<<dim3(16, 32), 256, 0, stream>>>(
            hb, wl + 1048576, b1 + l * 2048, nullptr, fbuf, nullptr, NROWS, 2048, 512);
        gemm_kernel<64, 128, false, true, false, false><<<dim3(4, 64), 256, 0, stream>>>(
            fbuf, wl + 2097152, b2 + l * 512, h, h2, nullptr, NROWS, 512, 2048);
        ln_kernel<<<NROWS, 512, 0, stream>>>(h2, ln2g + l * 512, ln2b + l * 512, h, hb);
    }

    ln_kernel<<<NROWS, 512, 0, stream>>>(h, lnfg, lnfb, h, hb);
    gemm_kernel<64, 128, false, false, false, false><<<dim3(4, 64), 256, 0, stream>>>(
        hb, lmwb, nullptr, nullptr, d_out, nullptr, NROWS, 512, 512);
}

// Round 6
// 874.559 us; speedup vs baseline: 1.1834x; 1.1834x over previous
//
#include <hip/hip_runtime.h>
#include <math.h>

#define D_MODEL 512
#define NHEAD   8
#define DKH     64
#define NLAYER  6
#define FFDIM   2048
#define VOCAB   512
#define BB      4
#define SS      1024
#define NROWS   4096

typedef unsigned short ushort_t;
typedef short short8 __attribute__((ext_vector_type(8)));
typedef float f32x4  __attribute__((ext_vector_type(4)));

__device__ __forceinline__ float bf2f(ushort_t u) {
    union { float f; unsigned int i; } x; x.i = ((unsigned int)u) << 16; return x.f;
}
__device__ __forceinline__ ushort_t f2bf(float f) {
    union { float f; unsigned int i; } x; x.f = f;
    unsigned int r = x.i + 0x7FFFu + ((x.i >> 16) & 1u);
    return (ushort_t)(r >> 16);
}
__device__ __forceinline__ void gload_lds16(const void* g, void* l) {
    __builtin_amdgcn_global_load_lds(
        (const __attribute__((address_space(1))) void*)g,
        (__attribute__((address_space(3))) void*)l, 16, 0, 0);
}

// ------------------------------------------------------------- weight convert
__global__ __launch_bounds__(256) void cvt_layer(
    const float* __restrict__ wq, const float* __restrict__ wk, const float* __restrict__ wv,
    const float* __restrict__ wo, const float* __restrict__ w1, const float* __restrict__ w2,
    const float* __restrict__ bq, const float* __restrict__ bk, const float* __restrict__ bv,
    ushort_t* __restrict__ wl, float* __restrict__ bqkv)
{
    int idx = blockIdx.x * 256 + threadIdx.x;   // quad id, 786432 total
    int e = idx * 4;
    float4 v;
    if (e < 786432) {
        if (e < 262144)       v = *(const float4*)(wq + e);
        else if (e < 524288)  v = *(const float4*)(wk + (e - 262144));
        else                  v = *(const float4*)(wv + (e - 524288));
    } else if (e < 1048576)   v = *(const float4*)(wo + (e - 786432));
    else if (e < 2097152)     v = *(const float4*)(w1 + (e - 1048576));
    else                      v = *(const float4*)(w2 + (e - 2097152));
    union { ushort_t u[4]; uint2 q; } pk;
    pk.u[0] = f2bf(v.x); pk.u[1] = f2bf(v.y); pk.u[2] = f2bf(v.z); pk.u[3] = f2bf(v.w);
    *(uint2*)(wl + e) = pk.q;
    if (idx < 384) {
        int b4 = idx * 4;
        float4 bv4;
        if (b4 < 512)       bv4 = *(const float4*)(bq + b4);
        else if (b4 < 1024) bv4 = *(const float4*)(bk + (b4 - 512));
        else                bv4 = *(const float4*)(bv + (b4 - 1024));
        *(float4*)(bqkv + b4) = bv4;
    }
}

__global__ __launch_bounds__(256) void cvt_simple(
    const float* __restrict__ src, ushort_t* __restrict__ dst)
{
    int e = (blockIdx.x * 256 + threadIdx.x) * 4;
    float4 v = *(const float4*)(src + e);
    union { ushort_t u[4]; uint2 q; } pk;
    pk.u[0] = f2bf(v.x); pk.u[1] = f2bf(v.y); pk.u[2] = f2bf(v.z); pk.u[3] = f2bf(v.w);
    *(uint2*)(dst + e) = pk.q;
}

__global__ __launch_bounds__(256) void maskbias_kernel(
    const int* __restrict__ am, float* __restrict__ mb)
{
    int i = blockIdx.x * 256 + threadIdx.x;
    if (i < NROWS) mb[i] = am[i] ? 0.f : -1e9f;
}

// ---------------------------------------------------------------- embedding
__global__ __launch_bounds__(512) void embed_kernel(
    const int* __restrict__ ids, const float* __restrict__ emb,
    float* __restrict__ xf, ushort_t* __restrict__ xb)
{
    int row = blockIdx.x;
    int d   = threadIdx.x;
    int s   = row & (SS - 1);
    int tok = ids[row];
    float div = expf(-(float)(d & ~1) * 0.0179889460390586f);
    float arg = (float)s * div;
    float pe  = (d & 1) ? cosf(arg) : sinf(arg);
    float v = emb[(size_t)tok * D_MODEL + d] * 22.62741699796952f + pe;
    xf[(size_t)row * D_MODEL + d] = v;
    xb[(size_t)row * D_MODEL + d] = f2bf(v);
}

// ---------------------------------------------------------------- layernorm
__global__ __launch_bounds__(512) void ln_kernel(
    const float* __restrict__ x, const float* __restrict__ g,
    const float* __restrict__ b, float* __restrict__ outf, ushort_t* __restrict__ outb)
{
    int row = blockIdx.x;
    int d   = threadIdx.x;
    int wave = d >> 6, lane = d & 63;
    __shared__ float red[8];

    float v = x[(size_t)row * D_MODEL + d];
    float s = v;
#pragma unroll
    for (int o = 32; o > 0; o >>= 1) s += __shfl_xor(s, o);
    if (lane == 0) red[wave] = s;
    __syncthreads();
    float tot = 0.f;
#pragma unroll
    for (int i = 0; i < 8; ++i) tot += red[i];
    float mu = tot * (1.0f / D_MODEL);
    float c  = v - mu;
    __syncthreads();
    float s2 = c * c;
#pragma unroll
    for (int o = 32; o > 0; o >>= 1) s2 += __shfl_xor(s2, o);
    if (lane == 0) red[wave] = s2;
    __syncthreads();
    float tot2 = 0.f;
#pragma unroll
    for (int i = 0; i < 8; ++i) tot2 += red[i];
    float var = tot2 * (1.0f / D_MODEL);
    float y = c * (1.0f / sqrtf(var + 1e-5f)) * g[d] + b[d];
    outf[(size_t)row * D_MODEL + d] = y;
    outb[(size_t)row * D_MODEL + d] = f2bf(y);
}

// ---------------------------------------------------------------- MFMA GEMM
// BK=64, XOR source-swizzled LDS (rule #21: linear gload_lds dest, inverse-
// swizzled global source, same XOR on ds_read). 4 waves, wave tile WMTxWNT.
template<int BM, int BN, bool RELU, bool RES, bool OBF16, bool VT>
__global__ __launch_bounds__(256) void gemm_kernel(
    const ushort_t* __restrict__ A, const ushort_t* __restrict__ W,
    const float* __restrict__ bias, const float* __restrict__ res,
    void* __restrict__ out, ushort_t* __restrict__ vtg, int M, int N, int K)
{
    constexpr int WMT = BM / 2, WNT = BN / 2;
    constexpr int FM = WMT / 16, FN = WNT / 16;
    constexpr int ISSA = BM / 32, ISSB = BN / 32;
    __shared__ ushort_t As[BM * 64];
    __shared__ ushort_t Bs[BN * 64];

    const int t = threadIdx.x;
    const int w = t >> 6, lane = t & 63;
    const int wr = w >> 1, wc = w & 1;
    const int col0 = blockIdx.x * BN;
    const int row0 = blockIdx.y * BM;
    const int lrow = lane & 15, kg = lane >> 4;
    const int srow = t >> 3;                       // 0..31
    const int sk8  = (t & 7) ^ ((t >> 3) & 7);     // pre-swizzled source k8

    f32x4 acc[FM][FN];
#pragma unroll
    for (int m = 0; m < FM; ++m)
#pragma unroll
        for (int n = 0; n < FN; ++n) acc[m][n] = (f32x4){0.f, 0.f, 0.f, 0.f};

    for (int k0 = 0; k0 < K; k0 += 64) {
#pragma unroll
        for (int i = 0; i < ISSA; ++i)
            gload_lds16(A + (size_t)(row0 + i * 32 + srow) * K + k0 + sk8 * 8,
                        (char*)As + i * 4096 + t * 16);
#pragma unroll
        for (int i = 0; i < ISSB; ++i)
            gload_lds16(W + (size_t)(col0 + i * 32 + srow) * K + k0 + sk8 * 8,
                        (char*)Bs + i * 4096 + t * 16);
        __syncthreads();
#pragma unroll
        for (int kk = 0; kk < 2; ++kk) {
            short8 af[FM], bfv[FN];
#pragma unroll
            for (int m = 0; m < FM; ++m) {
                const int row = wr * WMT + m * 16 + lrow;
                af[m] = *(const short8*)&As[row * 64 + (((kk * 4 + kg) ^ (lrow & 7)) << 3)];
            }
#pragma unroll
            for (int n = 0; n < FN; ++n) {
                const int col = wc * WNT + n * 16 + lrow;
                bfv[n] = *(const short8*)&Bs[col * 64 + (((kk * 4 + kg) ^ (lrow & 7)) << 3)];
            }
#pragma unroll
            for (int m = 0; m < FM; ++m)
#pragma unroll
                for (int n = 0; n < FN; ++n)
                    acc[m][n] = __builtin_amdgcn_mfma_f32_16x16x32_bf16(
                        af[m], bfv[n], acc[m][n], 0, 0, 0);
        }
        __syncthreads();
    }

    const int lrow4 = (lane >> 4) * 4;
    const int lcol  = lane & 15;
#pragma unroll
    for (int m = 0; m < FM; ++m)
#pragma unroll
        for (int n = 0; n < FN; ++n) {
            const int col = col0 + wc * WNT + n * 16 + lcol;
            const float bv = bias ? bias[col] : 0.f;
            const int row_base = row0 + wr * WMT + m * 16 + lrow4;
            if (VT && col >= 1024) {
                const int vh = (col - 1024) >> 6;
                const int vd = (col - 1024) & 63;
                const int bq = row_base >> 10;
                const int s0 = row_base & 1023;
                union { ushort_t u[4]; uint2 q; } pk;
#pragma unroll
                for (int j = 0; j < 4; ++j) pk.u[j] = f2bf(acc[m][n][j] + bv);
                *(uint2*)(vtg + ((size_t)(bq * 8 + vh) * 64 + vd) * 1024 + s0) = pk.q;
            } else {
#pragma unroll
                for (int j = 0; j < 4; ++j) {
                    const int row = row_base + j;
                    float v = acc[m][n][j] + bv;
                    if (RES)  v += res[(size_t)row * N + col];
                    if (RELU) v = fmaxf(v, 0.f);
                    if (OBF16) ((ushort_t*)out)[(size_t)row * N + col] = f2bf(v);
                    else       ((float*)out)[(size_t)row * N + col] = v;
                }
            }
        }
}

// ---------------------------------------------------------------- attention
// MFMA flash attention with key-split (flash-decoding). Block = (chunk, bh):
// chunk = (qt, [kb,ke)) from a static cost-descending schedule; 4 waves x 16 q
// of a 64-query tile. qt>=8 tiles split into two key chunks -> unnormalized
// partials (bf16 O, f32 m/l); qt<8 write o directly. K reg-double-buffered;
// V just-in-time; mask as f32 bias; wave-private swizzled P (no barriers).
__global__ __launch_bounds__(256) void attn_kernel(
    const ushort_t* __restrict__ qkv, const ushort_t* __restrict__ vtg,
    const float* __restrict__ mbias, ushort_t* __restrict__ o,
    ushort_t* __restrict__ pO, float* __restrict__ pml)
{
    constexpr int QT[24] = {15,15,14,7,14,13,13,12,6,12,11,11,10,5,10,9,9,8,4,8,3,2,1,0};
    constexpr int KBt[24]= {0,8,0,0,8,0,7,0,0,7,0,6,0,0,6,0,5,0,0,5,0,0,0,0};
    constexpr int KEt[24]= {8,16,8,8,15,7,14,7,7,13,6,12,6,6,11,5,10,5,5,9,4,3,2,1};

    __shared__ ushort_t Ps[4][16 * 64];

    const int t = threadIdx.x, w = t >> 6, l = t & 63;
    const int bid = blockIdx.x;
    const int c  = bid >> 5;
    const int bh = bid & 31, b = bh >> 3, h = bh & 7;
    const int qt = QT[c], kb = KBt[c], ke = KEt[c];
    const int q0 = qt * 64;
    const int lg = l >> 4, lr = l & 15;

    const ushort_t* qrow = qkv + (size_t)(b * SS + q0 + w * 16 + lr) * 1536 + h * 64;
    const short8 qa0 = *(const short8*)(qrow + lg * 8);
    const short8 qa1 = *(const short8*)(qrow + 32 + lg * 8);

    float m_run[4], l_run[4];
    f32x4 oacc[4];
#pragma unroll
    for (int j = 0; j < 4; ++j) { m_run[j] = -1e30f; l_run[j] = 0.f; }
#pragma unroll
    for (int nf = 0; nf < 4; ++nf) oacc[nf] = (f32x4){0.f, 0.f, 0.f, 0.f};

    ushort_t* myP = &Ps[w][0];
    const ushort_t* kb0 = qkv + (size_t)(b * SS) * 1536 + 512 + h * 64 + (size_t)lr * 1536 + lg * 8;
    const ushort_t* vb0 = vtg + ((size_t)bh * 64 + lr) * 1024 + lg * 8;
    const float*    mb0 = mbias + b * SS + lr;

    short8 kA[8], kB[8];
    float  mbA[4], mbB[4];

    auto PREFK = [&](short8* kf, float* mbf, int kt) {
#pragma unroll
        for (int nf = 0; nf < 4; ++nf) {
            const ushort_t* kr = kb0 + (size_t)(kt * 64 + 16 * nf) * 1536;
            kf[2 * nf]     = *(const short8*)(kr);
            kf[2 * nf + 1] = *(const short8*)(kr + 32);
            mbf[nf] = mb0[kt * 64 + 16 * nf];
        }
    };

    auto COMPUTE = [&](const short8* kf, const float* mbf, int kt) {
        short8 vf[8];
#pragma unroll
        for (int nf = 0; nf < 4; ++nf) {
            const ushort_t* vr = vb0 + (size_t)(16 * nf) * 1024 + kt * 64;
            vf[2 * nf]     = *(const short8*)(vr);
            vf[2 * nf + 1] = *(const short8*)(vr + 32);
        }
        f32x4 s[4];
#pragma unroll
        for (int nf = 0; nf < 4; ++nf) {
            f32x4 a = (f32x4){0.f, 0.f, 0.f, 0.f};
            a = __builtin_amdgcn_mfma_f32_16x16x32_bf16(qa0, kf[2 * nf],     a, 0, 0, 0);
            a = __builtin_amdgcn_mfma_f32_16x16x32_bf16(qa1, kf[2 * nf + 1], a, 0, 0, 0);
            s[nf] = a;
        }
        const int kk0 = kt * 64 + lr;
        const bool diag = (kt == qt);
        float p[4][4];
#pragma unroll
        for (int j = 0; j < 4; ++j) {
            const int qi = q0 + w * 16 + lg * 4 + j;
            float mx = -1e30f;
#pragma unroll
            for (int nf = 0; nf < 4; ++nf) {
                float sv = s[nf][j] * 0.125f + mbf[nf];
                if (diag && (kk0 + 16 * nf) > qi) sv = -1e9f;
                s[nf][j] = sv;
                mx = fmaxf(mx, sv);
            }
#pragma unroll
            for (int off = 1; off < 16; off <<= 1) mx = fmaxf(mx, __shfl_xor(mx, off));
            const float mnew = fmaxf(m_run[j], mx);
            float sum = 0.f;
#pragma unroll
            for (int nf = 0; nf < 4; ++nf) {
                float pv = __expf(s[nf][j] - mnew);
                p[nf][j] = pv;
                sum += pv;
            }
#pragma unroll
            for (int off = 1; off < 16; off <<= 1) sum += __shfl_xor(sum, off);
            const float rs = __expf(m_run[j] - mnew);
            l_run[j] = l_run[j] * rs + sum;
            m_run[j] = mnew;
#pragma unroll
            for (int nf = 0; nf < 4; ++nf) oacc[nf][j] *= rs;
        }
#pragma unroll
        for (int nf = 0; nf < 4; ++nf)
#pragma unroll
            for (int j = 0; j < 4; ++j) {
                const int q = lg * 4 + j;
                const int col = nf * 16 + lr;
                myP[q * 64 + (((col >> 3) ^ (q & 7)) << 3) + (col & 7)] = f2bf(p[nf][j]);
            }
        asm volatile("s_waitcnt lgkmcnt(0)" ::: "memory");
        __builtin_amdgcn_sched_barrier(0);
        const short8 pa0 = *(const short8*)&myP[lr * 64 + ((lg ^ (lr & 7)) << 3)];
        const short8 pa1 = *(const short8*)&myP[lr * 64 + (((4 + lg) ^ (lr & 7)) << 3)];
#pragma unroll
        for (int nf = 0; nf < 4; ++nf) {
            oacc[nf] = __builtin_amdgcn_mfma_f32_16x16x32_bf16(pa0, vf[2 * nf],     oacc[nf], 0, 0, 0);
            oacc[nf] = __builtin_amdgcn_mfma_f32_16x16x32_bf16(pa1, vf[2 * nf + 1], oacc[nf], 0, 0, 0);
        }
    };

    PREFK(kA, mbA, kb);
    for (int kt = kb; kt < ke; kt += 2) {
        PREFK(kB, mbB, (kt + 1 < ke) ? kt + 1 : ke - 1);
        COMPUTE(kA, mbA, kt);
        if (kt + 1 < ke) {
            PREFK(kA, mbA, (kt + 2 < ke) ? kt + 2 : ke - 1);
            COMPUTE(kB, mbB, kt + 1);
        }
    }

    if (qt >= 8) {
        // unnormalized partials
        const int g  = bh * 8 + (qt - 8);
        const int kc = (kb != 0) ? 1 : 0;
        const int pgi = g * 2 + kc;
#pragma unroll
        for (int j = 0; j < 4; ++j) {
            const int q = w * 16 + lg * 4 + j;
            if (lr == 0) {
                pml[(pgi * 64 + q) * 2 + 0] = m_run[j];
                pml[(pgi * 64 + q) * 2 + 1] = l_run[j];
            }
#pragma unroll
            for (int nf = 0; nf < 4; ++nf)
                pO[(size_t)pgi * 4096 + q * 64 + nf * 16 + lr] = f2bf(oacc[nf][j]);
        }
    } else {
#pragma unroll
        for (int nf = 0; nf < 4; ++nf)
#pragma unroll
            for (int j = 0; j < 4; ++j) {
                const int qi = q0 + w * 16 + lg * 4 + j;
                const int d  = nf * 16 + lr;
                o[(size_t)(b * SS + qi) * 512 + h * 64 + d] = f2bf(oacc[nf][j] / l_run[j]);
            }
    }
}

// combine two key-chunk partials for qt>=8 tiles
__global__ __launch_bounds__(256) void attn_combine(
    const ushort_t* __restrict__ pO, const float* __restrict__ pml,
    ushort_t* __restrict__ o)
{
    const int g = blockIdx.x;            // 0..255 = bh*8 + (qt-8)
    const int t = threadIdx.x, w = t >> 6, d = t & 63;
    const int bh = g >> 3, qt = (g & 7) + 8;
    const int b = bh >> 3, h = bh & 7;
#pragma unroll
    for (int qq = 0; qq < 16; ++qq) {
        const int q = w * 16 + qq;
        const float m0 = pml[((g * 2 + 0) * 64 + q) * 2 + 0];
        const float l0 = pml[((g * 2 + 0) * 64 + q) * 2 + 1];
        const float m1 = pml[((g * 2 + 1) * 64 + q) * 2 + 0];
        const float l1 = pml[((g * 2 + 1) * 64 + q) * 2 + 1];
        const float M  = fmaxf(m0, m1);
        const float s0 = __expf(m0 - M), s1 = __expf(m1 - M);
        const float den = s0 * l0 + s1 * l1;
        const float o0 = bf2f(pO[(size_t)(g * 2 + 0) * 4096 + q * 64 + d]);
        const float o1 = bf2f(pO[(size_t)(g * 2 + 1) * 4096 + q * 64 + d]);
        const float val = (s0 * o0 + s1 * o1) / den;
        const int token = b * SS + qt * 64 + q;
        o[(size_t)token * 512 + h * 64 + d] = f2bf(val);
    }
}

// ---------------------------------------------------------------- launch
extern "C" void kernel_launch(void* const* d_in, const int* in_sizes, int n_in,
                              void* d_out, int out_size, void* d_ws, size_t ws_size,
                              hipStream_t stream)
{
    const int*   ids   = (const int*)d_in[0];
    const int*   am    = (const int*)d_in[1];
    const float* emb   = (const float*)d_in[2];
    const float* wq    = (const float*)d_in[3];
    const float* bq    = (const float*)d_in[4];
    const float* wk    = (const float*)d_in[5];
    const float* bk    = (const float*)d_in[6];
    const float* wv    = (const float*)d_in[7];
    const float* bv    = (const float*)d_in[8];
    const float* wo    = (const float*)d_in[9];
    const float* bo    = (const float*)d_in[10];
    const float* ln1g  = (const float*)d_in[11];
    const float* ln1b  = (const float*)d_in[12];
    const float* w1    = (const float*)d_in[13];
    const float* b1    = (const float*)d_in[14];
    const float* w2    = (const float*)d_in[15];
    const float* b2    = (const float*)d_in[16];
    const float* ln2g  = (const float*)d_in[17];
    const float* ln2b  = (const float*)d_in[18];
    const float* lnfg  = (const float*)d_in[19];
    const float* lnfb  = (const float*)d_in[20];
    const float* lmw   = (const float*)d_in[21];

    char* base = (char*)d_ws;
    float*    h    = (float*)(base);                    //  8 MB
    float*    h2   = (float*)(base + 8388608);          //  8 MB (attn: vtg 4MB | pO 4MB)
    ushort_t* hb   = (ushort_t*)(base + 16777216);      //  4 MB
    ushort_t* act  = (ushort_t*)(base + 20971520);      // 16 MB shared
    ushort_t* qkvb = act;                               //   12 MB
    ushort_t* ob   = act + 6291456;                     //    4 MB
    ushort_t* fbuf = act;                               //   16 MB (after attn phase)
    ushort_t* wl   = (ushort_t*)(base + 37748736);      //  6 MB
    float*    bqkv = (float*)(base + 44040192);         //      6,144
    ushort_t* lmwb = (ushort_t*)(base + 44046336);      //    524,288
    float*    mbias= (float*)(base + 44570624);         //     16,384
    float*    pml  = (float*)(base + 44587008);         //    262,144 (end 44,849,152)
    ushort_t* vtg  = (ushort_t*)h2;                     //    4 MB, attn-phase only
    ushort_t* pO   = (ushort_t*)(base + 8388608 + 4194304); // 4 MB, attn-phase only

    cvt_simple<<<256, 256, 0, stream>>>(lmw, lmwb);
    maskbias_kernel<<<16, 256, 0, stream>>>(am, mbias);
    embed_kernel<<<NROWS, 512, 0, stream>>>(ids, emb, h, hb);

    for (int l = 0; l < NLAYER; ++l) {
        const size_t dd = (size_t)l * 262144;
        const size_t fd = (size_t)l * 1048576;
        cvt_layer<<<3072, 256, 0, stream>>>(wq + dd, wk + dd, wv + dd, wo + dd,
                                            w1 + fd, w2 + fd,
                                            bq + l * 512, bk + l * 512, bv + l * 512,
                                            wl, bqkv);
        // QKV fused GEMM (V written transposed to vtg by epilogue)
        gemm_kernel<64, 128, false, false, true, true><<<dim3(12, 64), 256, 0, stream>>>(
            hb, wl, bqkv, nullptr, qkvb, vtg, NROWS, 1536, 512);

        attn_kernel<<<768, 256, 0, stream>>>(qkvb, vtg, mbias, ob, pO, pml);
        attn_combine<<<256, 256, 0, stream>>>(pO, pml, ob);

        gemm_kernel<64, 64, false, true, false, false><<<dim3(8, 64), 256, 0, stream>>>(
            ob, wl + 786432, bo + l * 512, h, h2, nullptr, NROWS, 512, 512);
        ln_kernel<<<NROWS, 512, 0, stream>>>(h2, ln1g + l * 512, ln1b + l * 512, h, hb);

        gemm_kernel<64, 128, true, false, true, false><<<dim3(16, 64), 256, 0, stream>>>(
            hb, wl + 1048576, b1 + l * 2048, nullptr, fbuf, nullptr, NROWS, 2048, 512);
        gemm_kernel<64, 64, false, true, false, false><<<dim3(8, 64), 256, 0, stream>>>(
            fbuf, wl + 2097152, b2 + l * 512, h, h2, nullptr, NROWS, 512, 2048);
        ln_kernel<<<NROWS, 512, 0, stream>>>(h2, ln2g + l * 512, ln2b + l * 512, h, hb);
    }

    ln_kernel<<<NROWS, 512, 0, stream>>>(h, lnfg, lnfb, h, hb);
    gemm_kernel<64, 64, false, false, false, false><<<dim3(8, 64), 256, 0, stream>>>(
        hb, lmwb, nullptr, nullptr, d_out, nullptr, NROWS, 512, 512);
}